// Round 9
// baseline (4176.507 us; speedup 1.0000x reference)
//
#include <hip/hip_runtime.h>
#include <math.h>

#define N_NODES 50000
#define N_EDGES 1000000
#define LAYERS  3
#define G_GRAPHS 512
#define H 128
#define NG 50
#define PI_F 3.14159265358979323846f
#define LOG2_F 0.6931471805599453f

typedef __attribute__((ext_vector_type(4))) float f32x4;
typedef __attribute__((ext_vector_type(8))) short short8;   // 8 bf16 = 4 VGPRs (MFMA A/B frag)

__device__ __forceinline__ float ssp(float v) {
    float t = __expf(-fabsf(v));
    return fmaxf(v, 0.0f) + __logf(1.0f + t) - LOG2_F;
}

__device__ __forceinline__ unsigned short f2bf(float f) {
    unsigned u = __float_as_uint(f);
    unsigned r = (u + 0x7fff + ((u >> 16) & 1)) >> 16;
    return (unsigned short)r;
}
__device__ __forceinline__ float bf2f(unsigned short h) {
    return __uint_as_float((unsigned)h << 16);
}

// -------------------- CSR build: sort edges by dst --------------------
__global__ __launch_bounds__(256) void hist_kernel(const int* __restrict__ edst,
                                                   int* __restrict__ cnt) {
    int e = blockIdx.x * 256 + threadIdx.x;
    if (e < N_EDGES) atomicAdd(&cnt[edst[e]], 1);
}

// single-block exclusive scan, shuffle-based
__global__ __launch_bounds__(1024) void scan_kernel(const int* __restrict__ cnt,
                                                    int* __restrict__ cur) {
    __shared__ int wsum[16];
    __shared__ int carry_s;
    int tid = threadIdx.x;
    int wid = tid >> 6, lane = tid & 63;
    if (tid == 0) carry_s = 0;
    __syncthreads();
    for (int base = 0; base < N_NODES; base += 1024) {
        int i = base + tid;
        int v = (i < N_NODES) ? cnt[i] : 0;
        int s = v;
#pragma unroll
        for (int d = 1; d < 64; d <<= 1) {
            int t = __shfl_up(s, d, 64);
            if (lane >= d) s += t;
        }
        if (lane == 63) wsum[wid] = s;
        __syncthreads();
        if (wid == 0) {
            int ws = (lane < 16) ? wsum[lane] : 0;
#pragma unroll
            for (int d = 1; d < 16; d <<= 1) {
                int t = __shfl_up(ws, d, 64);
                if (lane >= d) ws += t;
            }
            if (lane < 16) wsum[lane] = ws;
        }
        __syncthreads();
        int waveoff = (wid > 0) ? wsum[wid - 1] : 0;
        int carry = carry_s;
        if (i < N_NODES) cur[i] = carry + waveoff + s - v;
        __syncthreads();
        if (tid == 1023) carry_s = carry + wsum[15];
    }
}

// scatter + (optionally) fused meta permute: Sp/Dp/Cp written in CSR order directly
template <bool WRITEMETA>
__global__ __launch_bounds__(256) void scatter_kernel(const int* __restrict__ esrc,
                                                      const int* __restrict__ edst,
                                                      const float* __restrict__ ew,
                                                      int* __restrict__ cur,
                                                      int* __restrict__ perm,
                                                      int* __restrict__ Sp,
                                                      int* __restrict__ Dp,
                                                      float* __restrict__ Cp) {
    int e = blockIdx.x * 256 + threadIdx.x;
    if (e < N_EDGES) {
        int d = edst[e];
        int p = atomicAdd(&cur[d], 1);
        perm[p] = e;
        if (WRITEMETA) {
            Sp[p] = esrc[e];
            Dp[p] = d;
            Cp[p] = 0.5f * (cosf(ew[e] * (PI_F / 10.0f)) + 1.0f);
        }
    }
}

// pattr[pos][0..63] bf16 = eattr[perm[pos]][0..49] (zero-padded). 8 threads/edge.
__global__ __launch_bounds__(256) void prep_attr(const int* __restrict__ perm,
                                                 const float* __restrict__ eattr,
                                                 unsigned short* __restrict__ pattr) {
    int t = blockIdx.x * 256 + threadIdx.x;
    int pos = t >> 3, kq = t & 7;
    if (pos >= N_EDGES) return;
    int ge = perm[pos];
    int k0 = kq * 8;
    float v[8] = {0.f, 0.f, 0.f, 0.f, 0.f, 0.f, 0.f, 0.f};
    const float* row = eattr + (size_t)ge * NG;
    if (k0 + 8 <= NG) {
#pragma unroll
        for (int q = 0; q < 4; ++q) {
            float2 a = *(const float2*)(row + k0 + 2 * q);
            v[2 * q] = a.x; v[2 * q + 1] = a.y;
        }
    } else if (k0 < NG) {            // k0 == 48
        float2 a = *(const float2*)(row + k0);
        v[0] = a.x; v[1] = a.y;
    }
    uint4 wv;
    wv.x = (unsigned)f2bf(v[0]) | ((unsigned)f2bf(v[1]) << 16);
    wv.y = (unsigned)f2bf(v[2]) | ((unsigned)f2bf(v[3]) << 16);
    wv.z = (unsigned)f2bf(v[4]) | ((unsigned)f2bf(v[5]) << 16);
    wv.w = (unsigned)f2bf(v[6]) | ((unsigned)f2bf(v[7]) << 16);
    *(uint4*)(pattr + (size_t)pos * 64 + k0) = wv;
}

// -------------------- filter weight pre-convert (single bf16) --------------------
__global__ __launch_bounds__(256) void conv_w(const float* __restrict__ mlp_w1,
                                              const float* __restrict__ mlp_w2,
                                              unsigned short* __restrict__ w1t,
                                              unsigned short* __restrict__ w2t) {
    int idx = blockIdx.x * 256 + threadIdx.x;
    const int n1 = LAYERS * 128 * 64;
    if (idx < n1) {
        int l = idx / (128 * 64);
        int rem = idx - l * 128 * 64;
        int col = rem >> 6, k = rem & 63;
        float v = (k < NG) ? mlp_w1[(size_t)l * NG * H + (size_t)k * H + col] : 0.f;
        w1t[idx] = f2bf(v);
        return;
    }
    int idx2 = idx - n1;
    if (idx2 < LAYERS * 128 * 128) {
        int l = idx2 / (128 * 128);
        int rem = idx2 - l * 128 * 128;
        int col = rem >> 7, k = rem & 127;
        w2t[idx2] = f2bf(mlp_w2[(size_t)l * H * H + (size_t)k * H + col]);
    }
}

// -------------------- node weight pre-convert, ALL matrices in one launch --------------------
// nw layout (16384-elem slots): [0..2]=cf_w1[l], [3..5]=cf_w2[l], [6..8]=lin_w[l], [9..]=ro_w1 (640x128)
__global__ __launch_bounds__(256) void conv_nodew_all(const float* __restrict__ cf_w1,
                                                      const float* __restrict__ cf_w2,
                                                      const float* __restrict__ lin_w,
                                                      const float* __restrict__ ro_w1,
                                                      unsigned short* __restrict__ hi,
                                                      unsigned short* __restrict__ lo) {
    int idx = blockIdx.x * 256 + threadIdx.x;
    const int SQ = LAYERS * 128 * 128;   // 49152
    float v; int dst;
    if (idx < 3 * SQ) {
        int fam = idx / SQ, rem = idx - fam * SQ;
        int l = rem / 16384, r2 = rem & 16383;
        int col = r2 >> 7, k = r2 & 127;
        const float* src = (fam == 0) ? cf_w1 : ((fam == 1) ? cf_w2 : lin_w);
        v = src[(size_t)l * 16384 + (size_t)k * 128 + col];
        dst = (fam * 3 + l) * 16384 + r2;
    } else {
        int j = idx - 3 * SQ;
        if (j >= 640 * 128) return;
        int col = j >> 7, k = j & 127;
        v = ro_w1[(size_t)k * 640 + col];
        dst = 3 * SQ + j;
    }
    unsigned short h16 = f2bf(v);
    hi[dst] = h16;
    lo[dst] = f2bf(v - bf2f(h16));
}

#define F_BIAS 1
#define F_POOL 8
#define F_EMB  16

// -------------------- MFMA node GEMM (split-bf16) --------------------
// F_EMB: A-row = relu(emb[z[row]]) and h is also written (fused init_h + x0).
template <int FLAGS>
__global__ __launch_bounds__(256, 4) void node_gemm_mfma(const float* __restrict__ A,
                                                         const unsigned short* __restrict__ BtHi,
                                                         const unsigned short* __restrict__ BtLo,
                                                         const float* __restrict__ bias,
                                                         float* __restrict__ Out,
                                                         const int* __restrict__ batch,
                                                         int nRows, int NC,
                                                         const int* __restrict__ z,
                                                         const float* __restrict__ emb,
                                                         float* __restrict__ hOut) {
    __shared__ __align__(16) char ldsHi[64 * 256];
    __shared__ __align__(16) char ldsLo[64 * 256];
    int tid = threadIdx.x;
    int rowBase = blockIdx.x * 64;
    int colOff = blockIdx.y * 128;
    int rlim = nRows - rowBase; if (rlim > 64) rlim = 64;

    for (int idx = tid; idx < 64 * 32; idx += 256) {
        int r = idx >> 5, q = idx & 31;
        float4 v = make_float4(0.f, 0.f, 0.f, 0.f);
        if (r < rlim) {
            if (FLAGS & F_EMB) {
                int zr = z[rowBase + r];
                v = *(const float4*)(emb + (size_t)zr * H + q * 4);
                v.x = fmaxf(v.x, 0.f); v.y = fmaxf(v.y, 0.f);
                v.z = fmaxf(v.z, 0.f); v.w = fmaxf(v.w, 0.f);
                *(float4*)(hOut + (size_t)(rowBase + r) * H + q * 4) = v;
            } else {
                v = *(const float4*)(A + (size_t)(rowBase + r) * H + q * 4);
            }
        }
        unsigned short h0 = f2bf(v.x), h1 = f2bf(v.y), h2 = f2bf(v.z), h3 = f2bf(v.w);
        unsigned short l0 = f2bf(v.x - bf2f(h0)), l1 = f2bf(v.y - bf2f(h1));
        unsigned short l2 = f2bf(v.z - bf2f(h2)), l3 = f2bf(v.w - bf2f(h3));
        int byte = (r << 8) + (q << 3);
        byte ^= (r & 7) << 4;
        *(uint2*)(ldsHi + byte) = make_uint2((unsigned)h0 | ((unsigned)h1 << 16),
                                             (unsigned)h2 | ((unsigned)h3 << 16));
        *(uint2*)(ldsLo + byte) = make_uint2((unsigned)l0 | ((unsigned)l1 << 16),
                                             (unsigned)l2 | ((unsigned)l3 << 16));
    }
    __syncthreads();

    int w = tid >> 6, lane = tid & 63;
    int lg = lane >> 4, cg = lane & 15;
    int swA = (cg & 7) << 4;

    f32x4 acc[4][2];
#pragma unroll
    for (int n = 0; n < 2; ++n) {
        float b = (FLAGS & F_BIAS) ? bias[colOff + w * 32 + n * 16 + cg] : 0.f;
        f32x4 t = {b, b, b, b};
#pragma unroll
        for (int m = 0; m < 4; ++m) acc[m][n] = t;
    }

#pragma unroll
    for (int kc = 0; kc < 4; ++kc) {
        short8 aHi[4], aLo[4], bHi[2], bLo[2];
#pragma unroll
        for (int m = 0; m < 4; ++m) {
            int byte = ((m * 16 + cg) << 8) + ((kc * 32 + lg * 8) << 1);
            aHi[m] = *(short8*)(ldsHi + (byte ^ swA));
            aLo[m] = *(short8*)(ldsLo + (byte ^ swA));
        }
#pragma unroll
        for (int n = 0; n < 2; ++n) {
            size_t off = (size_t)(colOff + w * 32 + n * 16 + cg) * 128 + kc * 32 + lg * 8;
            bHi[n] = *(const short8*)(BtHi + off);
            bLo[n] = *(const short8*)(BtLo + off);
        }
#pragma unroll
        for (int m = 0; m < 4; ++m)
#pragma unroll
            for (int n = 0; n < 2; ++n) {
                acc[m][n] = __builtin_amdgcn_mfma_f32_16x16x32_bf16(aHi[m], bHi[n], acc[m][n], 0, 0, 0);
                acc[m][n] = __builtin_amdgcn_mfma_f32_16x16x32_bf16(aLo[m], bHi[n], acc[m][n], 0, 0, 0);
                acc[m][n] = __builtin_amdgcn_mfma_f32_16x16x32_bf16(aHi[m], bLo[n], acc[m][n], 0, 0, 0);
            }
    }

    if (FLAGS & F_POOL) {
        int cur = -1;
        float s[2] = {0.f, 0.f};
#pragma unroll
        for (int m = 0; m < 4; ++m) {
#pragma unroll
            for (int i = 0; i < 4; ++i) {
                int row = m * 16 + lg * 4 + i;
                int b = (row < rlim) ? batch[rowBase + row] : -1;
                if (b != cur) {
                    if (cur >= 0) {
#pragma unroll
                        for (int n = 0; n < 2; ++n)
                            unsafeAtomicAdd(Out + (size_t)cur * NC + colOff + w * 32 + n * 16 + cg, s[n]);
                    }
                    cur = b;
                    s[0] = 0.f; s[1] = 0.f;
                }
                if (b >= 0) {
#pragma unroll
                    for (int n = 0; n < 2; ++n) s[n] += ssp(acc[m][n][i]);
                }
            }
        }
        if (cur >= 0) {
#pragma unroll
            for (int n = 0; n < 2; ++n)
                unsafeAtomicAdd(Out + (size_t)cur * NC + colOff + w * 32 + n * 16 + cg, s[n]);
        }
    } else {
#pragma unroll
        for (int m = 0; m < 4; ++m)
#pragma unroll
            for (int i = 0; i < 4; ++i) {
                int row = m * 16 + lg * 4 + i;
                if (row < rlim) {
#pragma unroll
                    for (int n = 0; n < 2; ++n)
                        Out[(size_t)(rowBase + row) * NC + colOff + w * 32 + n * 16 + cg] = acc[m][n][i];
                }
            }
    }
}

// -------------------- fused per-layer tail: h += ssp(agg@W2+b2)@WL+bl ; optional x_next = h@W1n --------------------
// Also re-zeroes agg while staging it (removes per-layer memset).
template <bool XNEXT>
__global__ __launch_bounds__(256, 4) void node_gemm2_mfma(float* __restrict__ Agg,
                                                          const unsigned short* __restrict__ W2hi,
                                                          const unsigned short* __restrict__ W2lo,
                                                          const float* __restrict__ b2,
                                                          const unsigned short* __restrict__ WLhi,
                                                          const unsigned short* __restrict__ WLlo,
                                                          const float* __restrict__ bl,
                                                          const unsigned short* __restrict__ W1nhi,
                                                          const unsigned short* __restrict__ W1nlo,
                                                          float* __restrict__ Hio,
                                                          float* __restrict__ xout,
                                                          int nRows) {
    __shared__ __align__(16) char ldsHi[64 * 256];
    __shared__ __align__(16) char ldsLo[64 * 256];
    int tid = threadIdx.x;
    int rowBase = blockIdx.x * 64;
    int rlim = nRows - rowBase; if (rlim > 64) rlim = 64;

    for (int idx = tid; idx < 64 * 32; idx += 256) {
        int r = idx >> 5, q = idx & 31;
        float4 v = make_float4(0.f, 0.f, 0.f, 0.f);
        if (r < rlim) {
            float* p = Agg + (size_t)(rowBase + r) * H + q * 4;
            v = *(float4*)p;
            *(float4*)p = make_float4(0.f, 0.f, 0.f, 0.f);   // zero agg for next layer
        }
        unsigned short h0 = f2bf(v.x), h1 = f2bf(v.y), h2 = f2bf(v.z), h3 = f2bf(v.w);
        unsigned short l0 = f2bf(v.x - bf2f(h0)), l1 = f2bf(v.y - bf2f(h1));
        unsigned short l2 = f2bf(v.z - bf2f(h2)), l3 = f2bf(v.w - bf2f(h3));
        int byte = (r << 8) + (q << 3);
        byte ^= (r & 7) << 4;
        *(uint2*)(ldsHi + byte) = make_uint2((unsigned)h0 | ((unsigned)h1 << 16),
                                             (unsigned)h2 | ((unsigned)h3 << 16));
        *(uint2*)(ldsLo + byte) = make_uint2((unsigned)l0 | ((unsigned)l1 << 16),
                                             (unsigned)l2 | ((unsigned)l3 << 16));
    }
    __syncthreads();

    int w = tid >> 6, lane = tid & 63;
    int lg = lane >> 4, cg = lane & 15;
    int swA = (cg & 7) << 4;

    // ---- GEMM-A: x1 = agg @ W2 + b2 ----
    f32x4 acc[4][2];
#pragma unroll
    for (int n = 0; n < 2; ++n) {
        float b = b2[w * 32 + n * 16 + cg];
        f32x4 t = {b, b, b, b};
#pragma unroll
        for (int m = 0; m < 4; ++m) acc[m][n] = t;
    }
#pragma unroll
    for (int kc = 0; kc < 4; ++kc) {
        short8 aHi[4], aLo[4], bHi[2], bLo[2];
#pragma unroll
        for (int m = 0; m < 4; ++m) {
            int byte = ((m * 16 + cg) << 8) + ((kc * 32 + lg * 8) << 1);
            aHi[m] = *(short8*)(ldsHi + (byte ^ swA));
            aLo[m] = *(short8*)(ldsLo + (byte ^ swA));
        }
#pragma unroll
        for (int n = 0; n < 2; ++n) {
            size_t off = (size_t)(w * 32 + n * 16 + cg) * 128 + kc * 32 + lg * 8;
            bHi[n] = *(const short8*)(W2hi + off);
            bLo[n] = *(const short8*)(W2lo + off);
        }
#pragma unroll
        for (int m = 0; m < 4; ++m)
#pragma unroll
            for (int n = 0; n < 2; ++n) {
                acc[m][n] = __builtin_amdgcn_mfma_f32_16x16x32_bf16(aHi[m], bHi[n], acc[m][n], 0, 0, 0);
                acc[m][n] = __builtin_amdgcn_mfma_f32_16x16x32_bf16(aLo[m], bHi[n], acc[m][n], 0, 0, 0);
                acc[m][n] = __builtin_amdgcn_mfma_f32_16x16x32_bf16(aHi[m], bLo[n], acc[m][n], 0, 0, 0);
            }
    }
    __syncthreads();

    // ---- write ssp(x1) back to LDS as split-bf16 [row][col] ----
#pragma unroll
    for (int m = 0; m < 4; ++m)
#pragma unroll
        for (int n = 0; n < 2; ++n)
#pragma unroll
            for (int i = 0; i < 4; ++i) {
                int row = m * 16 + lg * 4 + i;
                int col = w * 32 + n * 16 + cg;
                float v = ssp(acc[m][n][i]);
                unsigned short hh = f2bf(v);
                unsigned short ll = f2bf(v - bf2f(hh));
                int byte = (row << 8) + (col << 1);
                byte ^= (row & 7) << 4;
                *(unsigned short*)(ldsHi + byte) = hh;
                *(unsigned short*)(ldsLo + byte) = ll;
            }
    __syncthreads();

    // ---- GEMM-B: dh = x1s @ WL + bl ----
    f32x4 acc2[4][2];
#pragma unroll
    for (int n = 0; n < 2; ++n) {
        float b = bl[w * 32 + n * 16 + cg];
        f32x4 t = {b, b, b, b};
#pragma unroll
        for (int m = 0; m < 4; ++m) acc2[m][n] = t;
    }
#pragma unroll
    for (int kc = 0; kc < 4; ++kc) {
        short8 aHi[4], aLo[4], bHi[2], bLo[2];
#pragma unroll
        for (int m = 0; m < 4; ++m) {
            int byte = ((m * 16 + cg) << 8) + ((kc * 32 + lg * 8) << 1);
            aHi[m] = *(short8*)(ldsHi + (byte ^ swA));
            aLo[m] = *(short8*)(ldsLo + (byte ^ swA));
        }
#pragma unroll
        for (int n = 0; n < 2; ++n) {
            size_t off = (size_t)(w * 32 + n * 16 + cg) * 128 + kc * 32 + lg * 8;
            bHi[n] = *(const short8*)(WLhi + off);
            bLo[n] = *(const short8*)(WLlo + off);
        }
#pragma unroll
        for (int m = 0; m < 4; ++m)
#pragma unroll
            for (int n = 0; n < 2; ++n) {
                acc2[m][n] = __builtin_amdgcn_mfma_f32_16x16x32_bf16(aHi[m], bHi[n], acc2[m][n], 0, 0, 0);
                acc2[m][n] = __builtin_amdgcn_mfma_f32_16x16x32_bf16(aLo[m], bHi[n], acc2[m][n], 0, 0, 0);
                acc2[m][n] = __builtin_amdgcn_mfma_f32_16x16x32_bf16(aHi[m], bLo[n], acc2[m][n], 0, 0, 0);
            }
    }

    if (XNEXT) {
        __syncthreads();   // all waves done with GEMM-B's LDS reads before restage
        // ---- h_new = h + dh -> global AND split-LDS for GEMM-C ----
#pragma unroll
        for (int m = 0; m < 4; ++m)
#pragma unroll
            for (int n = 0; n < 2; ++n)
#pragma unroll
                for (int i = 0; i < 4; ++i) {
                    int row = m * 16 + lg * 4 + i;
                    int col = w * 32 + n * 16 + cg;
                    float hnew = 0.f;
                    if (row < rlim) {
                        float* p = Hio + (size_t)(rowBase + row) * H + col;
                        hnew = *p + acc2[m][n][i];
                        *p = hnew;
                    }
                    unsigned short hh = f2bf(hnew);
                    unsigned short ll = f2bf(hnew - bf2f(hh));
                    int byte = (row << 8) + (col << 1);
                    byte ^= (row & 7) << 4;
                    *(unsigned short*)(ldsHi + byte) = hh;
                    *(unsigned short*)(ldsLo + byte) = ll;
                }
        __syncthreads();

        // ---- GEMM-C: x_next = h_new @ W1n (no bias) ----
        f32x4 acc3[4][2];
#pragma unroll
        for (int n = 0; n < 2; ++n) {
            f32x4 t = {0.f, 0.f, 0.f, 0.f};
#pragma unroll
            for (int m = 0; m < 4; ++m) acc3[m][n] = t;
        }
#pragma unroll
        for (int kc = 0; kc < 4; ++kc) {
            short8 aHi[4], aLo[4], bHi[2], bLo[2];
#pragma unroll
            for (int m = 0; m < 4; ++m) {
                int byte = ((m * 16 + cg) << 8) + ((kc * 32 + lg * 8) << 1);
                aHi[m] = *(short8*)(ldsHi + (byte ^ swA));
                aLo[m] = *(short8*)(ldsLo + (byte ^ swA));
            }
#pragma unroll
            for (int n = 0; n < 2; ++n) {
                size_t off = (size_t)(w * 32 + n * 16 + cg) * 128 + kc * 32 + lg * 8;
                bHi[n] = *(const short8*)(W1nhi + off);
                bLo[n] = *(const short8*)(W1nlo + off);
            }
#pragma unroll
            for (int m = 0; m < 4; ++m)
#pragma unroll
                for (int n = 0; n < 2; ++n) {
                    acc3[m][n] = __builtin_amdgcn_mfma_f32_16x16x32_bf16(aHi[m], bHi[n], acc3[m][n], 0, 0, 0);
                    acc3[m][n] = __builtin_amdgcn_mfma_f32_16x16x32_bf16(aLo[m], bHi[n], acc3[m][n], 0, 0, 0);
                    acc3[m][n] = __builtin_amdgcn_mfma_f32_16x16x32_bf16(aHi[m], bLo[n], acc3[m][n], 0, 0, 0);
                }
        }
#pragma unroll
        for (int m = 0; m < 4; ++m)
#pragma unroll
            for (int i = 0; i < 4; ++i) {
                int row = m * 16 + lg * 4 + i;
                if (row < rlim) {
#pragma unroll
                    for (int n = 0; n < 2; ++n)
                        xout[(size_t)(rowBase + row) * H + w * 32 + n * 16 + cg] = acc3[m][n][i];
                }
            }
    } else {
#pragma unroll
        for (int m = 0; m < 4; ++m)
#pragma unroll
            for (int i = 0; i < 4; ++i) {
                int row = m * 16 + lg * 4 + i;
                if (row < rlim) {
#pragma unroll
                    for (int n = 0; n < 2; ++n) {
                        float* p = Hio + (size_t)(rowBase + row) * H + w * 32 + n * 16 + cg;
                        *p += acc2[m][n][i];
                    }
                }
            }
    }
}

// -------------------- fused edge kernel v8: round-4 v3b structure, PERSISTENT blocks --------------------
// R8 post-mortem: fire-and-forget atomics cost 528MB write-amplification; v3b's LDS run-combine
// epilogue (425us, WRITE 32MB) was the best measured. Restored verbatim + persistent-loop:
// grid = 1280 (5 blocks/CU, the LDS residency limit) looping over edge-groups.
// Loop-safety: accT zeroed once + re-zeroed by the reading thread in the store loop;
// RunDst written AFTER barrier1 (so store(i) readers can't race next iter's write);
// barrier1(i+1) happens-after all stores(i), so atomics(i+1) are ordered w.r.t. rezero(i).
#define RUNCAP 8
template <bool IDXP, bool ATTRP>
__global__ __launch_bounds__(256, 5) void edge_kernel(
        const unsigned short* __restrict__ pattr,
        const float* __restrict__ eattr,
        const int* __restrict__ perm,
        const int* __restrict__ esrc,
        const int* __restrict__ edst,
        const float* __restrict__ ew,
        const int* __restrict__ Sp,
        const int* __restrict__ Dp,
        const float* __restrict__ Cp,
        const unsigned short* __restrict__ W1t,
        const float* __restrict__ b1,
        const unsigned short* __restrict__ W2t,
        const float* __restrict__ b2,
        const float* __restrict__ x,
        float* __restrict__ agg) {
    // LDS map (bytes):
    // [0,     8192)  attr bf16 [64 rows][64 k], xor-swizzled
    // [8192, 24576)  T bf16 [64][128], xor-swizzled
    // [24576,28800)  accT fp32 [8 runs][132]
    // [28800,28832)  RunDst[8]
    __shared__ __align__(16) char lds[28832];
    float* accT = (float*)(lds + 24576);
    int* RunDst = (int*)(lds + 28800);

    int tid = threadIdx.x;
    int w = tid >> 6, lane = tid & 63;
    int lg = lane >> 4, cg = lane & 15;
    int eB = w * 16 + cg;
    int swz = (eB & 7) << 4;
    int le0 = w * 16 + lg * 4;

    // zero accT ONCE; store loop re-zeroes what it reads each iteration
    for (int i = tid; i < RUNCAP * 132; i += 256) accT[i] = 0.f;

    const int NGRP = N_EDGES / 64;
    for (int grp = blockIdx.x; grp < NGRP; grp += gridDim.x) {
        int e0 = grp * 64;

        // per-lane meta for block-edge l = lane
        int ge = 0;
        if (!ATTRP || !IDXP) ge = perm[e0 + lane];
        int S, D; float C;
        if (IDXP) {
            S = Sp[e0 + lane]; D = Dp[e0 + lane]; C = Cp[e0 + lane];
        } else {
            S = esrc[ge]; D = edst[ge];
            C = 0.5f * (cosf(ew[ge] * (PI_F / 10.0f)) + 1.0f);
        }
        int prevd = -1, nextd = -1;
        if (e0 > 0)            prevd = IDXP ? Dp[e0 - 1]  : edst[perm[e0 - 1]];
        if (e0 + 64 < NGRP * 64) nextd = IDXP ? Dp[e0 + 64] : edst[perm[e0 + 64]];

        // ---- stage attr rows for THIS wave: rows w*16 .. w*16+15 (wave-local) ----
        if (ATTRP) {
#pragma unroll
            for (int half = 0; half < 2; ++half) {
                int idx2 = lane + half * 64;
                int row = w * 16 + (idx2 >> 3);
                int q = idx2 & 7;
                uint4 v = *(const uint4*)(pattr + (((size_t)(e0 + row)) << 6) + q * 8);
                int byte = (row << 7) + (q << 4);
                byte ^= (row & 7) << 4;
                *(uint4*)(lds + byte) = v;
            }
        } else {
            int row = w * 16 + (lane >> 2);
            int grow = __shfl(ge, row);
            int jbase = (lane & 3) * 8;
#pragma unroll
            for (int j = 0; j < 8; ++j) {
                int k2 = jbase + j;
                float a0 = 0.f, a1 = 0.f;
                if (k2 < 25) {
                    float2 t = *(const float2*)(eattr + (size_t)grow * NG + 2 * k2);
                    a0 = t.x; a1 = t.y;
                }
                unsigned p = (unsigned)f2bf(a0) | ((unsigned)f2bf(a1) << 16);
                int byte = (row << 7) + (k2 << 2);
                byte ^= (row & 7) << 4;
                *(unsigned*)(lds + byte) = p;
            }
        }

        // ---- GEMM1': D[Tcol][edge] = W1t @ attr^T + b1 (wave-local LDS, in-order DS) ----
        f32x4 acc1[8];
#pragma unroll
        for (int mt = 0; mt < 8; ++mt)
            acc1[mt] = *(const f32x4*)(b1 + mt * 16 + lg * 4);
#pragma unroll
        for (int kc = 0; kc < 2; ++kc) {
            int byteB = (eB << 7) + (kc << 6) + (lg << 4);
            short8 bfrag = *(short8*)(lds + (byteB ^ swz));
#pragma unroll
            for (int mt = 0; mt < 8; ++mt) {
                short8 afrag = *(const short8*)(W1t + ((mt * 16 + cg) << 6) + (kc << 5) + (lg << 3));
                acc1[mt] = __builtin_amdgcn_mfma_f32_16x16x32_bf16(afrag, bfrag, acc1[mt], 0, 0, 0);
            }
        }
        // T = ssp(acc1) -> LDS bf16 (wave-local rows; no barrier)
#pragma unroll
        for (int mt = 0; mt < 8; ++mt) {
            f32x4 v = acc1[mt];
            unsigned p0 = (unsigned)f2bf(ssp(v[0])) | ((unsigned)f2bf(ssp(v[1])) << 16);
            unsigned p1 = (unsigned)f2bf(ssp(v[2])) | ((unsigned)f2bf(ssp(v[3])) << 16);
            int byte = 8192 + (eB << 8) + (mt << 5) + (lg << 3);
            *(uint2*)(lds + (byte ^ swz)) = make_uint2(p0, p1);
        }

        // ---- GEMM2: Wf[edge][col] = T @ W2t^T + b2 (wave-local reads) ----
        f32x4 acc2[8];
#pragma unroll
        for (int n = 0; n < 8; ++n) {
            float bb = b2[n * 16 + cg];
            f32x4 t = {bb, bb, bb, bb};
            acc2[n] = t;
        }
#pragma unroll
        for (int kc = 0; kc < 4; ++kc) {
            int byteA = 8192 + (eB << 8) + (kc << 6) + (lg << 4);
            short8 afrag = *(short8*)(lds + (byteA ^ swz));
#pragma unroll
            for (int n = 0; n < 8; ++n) {
                short8 bfrag = *(const short8*)(W2t + ((n * 16 + cg) << 7) + (kc << 5) + (lg << 3));
                acc2[n] = __builtin_amdgcn_mfma_f32_16x16x32_bf16(afrag, bfrag, acc2[n], 0, 0, 0);
            }
        }

        // ---- x prefetch (vmcnt stays in flight across barrier1) ----
        float xv[4][8];
#pragma unroll
        for (int i = 0; i < 4; ++i) {
            int sle = __shfl(S, le0 + i);
            const float* xrow = x + (size_t)sle * H + cg;
#pragma unroll
            for (int n = 0; n < 8; ++n) xv[i][n] = xrow[n * 16];
        }

        // ---- run-id scan in registers (redundant per wave; no LDS) ----
        int dprev = __shfl_up(D, 1, 64);
        int flag = (lane > 0 && D != dprev) ? 1 : 0;
        int rid = flag;
#pragma unroll
        for (int s2 = 1; s2 < 64; s2 <<= 1) {
            int o = __shfl_up(rid, s2, 64);
            if (lane >= s2) rid += o;
        }
        int nruns = __shfl(rid, 63) + 1;

        // barrier1: prior iteration's store+rezero complete on ALL waves; accT clean
        asm volatile("s_waitcnt lgkmcnt(0)" ::: "memory");
        __builtin_amdgcn_s_barrier();
        asm volatile("" ::: "memory");

        // RunDst written AFTER barrier1 (store(i-1) readers are guaranteed done)
        if (w == 0 && (lane == 0 || flag) && rid < RUNCAP) RunDst[rid] = D;

        // ---- per-run accumulation: LDS atomics (runs < RUNCAP) or global atomics ----
        int curR = -1, curD = 0;
        float part[8];
#pragma unroll
        for (int i = 0; i < 4; ++i) {
            int le = le0 + i;
            int r  = __shfl(rid, le);
            int dd = __shfl(D, le);
            float cf = __shfl(C, le);
            float m[8];
#pragma unroll
            for (int n = 0; n < 8; ++n) m[n] = xv[i][n] * acc2[n][i] * cf;
            if (r != curR) {
                if (curR >= 0) {
                    if (curR < RUNCAP) {
#pragma unroll
                        for (int n = 0; n < 8; ++n)
                            atomicAdd(accT + curR * 132 + n * 16 + cg, part[n]);
                    } else {
#pragma unroll
                        for (int n = 0; n < 8; ++n)
                            unsafeAtomicAdd(agg + (size_t)curD * H + n * 16 + cg, part[n]);
                    }
                }
                curR = r; curD = dd;
#pragma unroll
                for (int n = 0; n < 8; ++n) part[n] = m[n];
            } else {
#pragma unroll
                for (int n = 0; n < 8; ++n) part[n] += m[n];
            }
        }
        if (curR < RUNCAP) {
#pragma unroll
            for (int n = 0; n < 8; ++n)
                atomicAdd(accT + curR * 132 + n * 16 + cg, part[n]);
        } else {
#pragma unroll
            for (int n = 0; n < 8; ++n)
                unsafeAtomicAdd(agg + (size_t)curD * H + n * 16 + cg, part[n]);
        }

        // barrier2: all LDS atomics + RunDst writes done
        asm volatile("s_waitcnt lgkmcnt(0)" ::: "memory");
        __builtin_amdgcn_s_barrier();
        asm volatile("" ::: "memory");

        // ---- store complete runs + RE-ZERO read words (same thread); boundary runs atomic ----
        int nstore = (nruns < RUNCAP) ? nruns : RUNCAP;
        for (int idx = tid; idx < nstore * H; idx += 256) {
            int r = idx >> 7, c = idx & 127;
            float v = accT[r * 132 + c];
            accT[r * 132 + c] = 0.f;        // clean for next group (atomic range ⊆ store range)
            int d = RunDst[r];
            bool shared_run = (r == 0 && d == prevd) || (r == nruns - 1 && d == nextd);
            float* p = agg + (size_t)d * H + c;
            if (shared_run) unsafeAtomicAdd(p, v);
            else *p = v;
        }
    }
}

// -------------------- out = ssp(pooled@ro_w2 + b2) @ ro_w3 + b3 --------------------
__global__ __launch_bounds__(128) void final_out(const float* __restrict__ pooled,
                                                 const float* __restrict__ ro_w2,
                                                 const float* __restrict__ ro_b2,
                                                 const float* __restrict__ ro_w3,
                                                 const float* __restrict__ ro_b3,
                                                 float* __restrict__ out) {
    int g = blockIdx.x;
    int c = threadIdx.x;
    float acc = ro_b2[c];
    const float* pr = pooled + (size_t)g * (5 * H);
    for (int k = 0; k < 5 * H; ++k) acc = fmaf(pr[k], ro_w2[(size_t)k * H + c], acc);
    float v = ssp(acc) * ro_w3[c];
    __shared__ float red[128];
    red[c] = v;
    __syncthreads();
    for (int s = 64; s > 0; s >>= 1) {
        if (c < s) red[c] += red[c + s];
        __syncthreads();
    }
    if (c == 0) out[g] = red[0] + ro_b3[0];
}

extern "C" void kernel_launch(void* const* d_in, const int* in_sizes, int n_in,
                              void* d_out, int out_size, void* d_ws, size_t ws_size,
                              hipStream_t stream) {
    const int* z     = (const int*)d_in[0];
    const int* esrc  = (const int*)d_in[1];
    const int* edst  = (const int*)d_in[2];
    const int* batch = (const int*)d_in[3];
    const float* ew    = (const float*)d_in[5];
    const float* eattr = (const float*)d_in[6];
    const float* emb   = (const float*)d_in[7];
    const float* mlp_w1 = (const float*)d_in[8];
    const float* mlp_b1 = (const float*)d_in[9];
    const float* mlp_w2 = (const float*)d_in[10];
    const float* mlp_b2 = (const float*)d_in[11];
    const float* cf_w1  = (const float*)d_in[12];
    const float* cf_w2  = (const float*)d_in[13];
    const float* cf_b2  = (const float*)d_in[14];
    const float* lin_w  = (const float*)d_in[15];
    const float* lin_b  = (const float*)d_in[16];
    const float* ro_w1  = (const float*)d_in[17];
    const float* ro_b1  = (const float*)d_in[18];
    const float* ro_w2  = (const float*)d_in[19];
    const float* ro_b2  = (const float*)d_in[20];
    const float* ro_w3  = (const float*)d_in[21];
    const float* ro_b3  = (const float*)d_in[22];
    float* out = (float*)d_out;

    char* wp = (char*)d_ws;
    auto alloc = [&](size_t bytes) {
        char* p = wp;
        wp += (bytes + 255) & ~(size_t)255;
        return p;
    };
    float* h      = (float*)alloc((size_t)N_NODES * H * 4);
    float* x      = (float*)alloc((size_t)N_NODES * H * 4);
    float* agg    = (float*)alloc((size_t)N_NODES * H * 4);
    float* pooled = (float*)alloc((size_t)G_GRAPHS * 5 * H * 4);
    int*   cnt    = (int*)alloc(N_NODES * 4);
    int*   cur    = (int*)alloc(N_NODES * 4);
    int*   perm   = (int*)alloc((size_t)N_EDGES * 4);
    unsigned short* w1t  = (unsigned short*)alloc((size_t)LAYERS * 128 * 64 * 2);
    unsigned short* w2t  = (unsigned short*)alloc((size_t)LAYERS * 128 * 128 * 2);
    unsigned short* nwhi = (unsigned short*)alloc((size_t)(9 * 16384 + 640 * 128) * 2);
    unsigned short* nwlo = (unsigned short*)alloc((size_t)(9 * 16384 + 640 * 128) * 2);
    int*   Sp = (int*)alloc((size_t)N_EDGES * 4);
    int*   Dp = (int*)alloc((size_t)N_EDGES * 4);
    float* Cp = (float*)alloc((size_t)N_EDGES * 4);
    size_t used_idx = (size_t)(wp - (char*)d_ws);
    unsigned short* pattr = (unsigned short*)alloc((size_t)N_EDGES * 64 * 2);
    size_t used_attr = (size_t)(wp - (char*)d_ws);

    bool idxp  = ws_size >= used_idx;
    bool attrp = ws_size >= used_attr;

    conv_w<<<(LAYERS * 128 * 64 + LAYERS * 128 * 128 + 255) / 256, 256, 0, stream>>>(
        mlp_w1, mlp_w2, w1t, w2t);
    conv_nodew_all<<<(3 * LAYERS * 128 * 128 + 640 * 128 + 255) / 256, 256, 0, stream>>>(
        cf_w1, cf_w2, lin_w, ro_w1, nwhi, nwlo);

    hipMemsetAsync(cnt, 0, N_NODES * sizeof(int), stream);
    hist_kernel<<<(N_EDGES + 255) / 256, 256, 0, stream>>>(edst, cnt);
    scan_kernel<<<1, 1024, 0, stream>>>(cnt, cur);
    if (idxp)
        scatter_kernel<true><<<(N_EDGES + 255) / 256, 256, 0, stream>>>(
            esrc, edst, ew, cur, perm, Sp, Dp, Cp);
    else
        scatter_kernel<false><<<(N_EDGES + 255) / 256, 256, 0, stream>>>(
            esrc, edst, ew, cur, perm, Sp, Dp, Cp);
    if (attrp)
        prep_attr<<<(N_EDGES * 8 + 255) / 256, 256, 0, stream>>>(perm, eattr, pattr);

    int rowTiles = (N_NODES + 63) / 64;  // 782

    // fused: h = relu(emb[z]); x = h @ cf_w1[0]
    node_gemm_mfma<F_EMB><<<dim3(rowTiles, 1), 256, 0, stream>>>(
        nullptr, nwhi, nwlo, nullptr, x, nullptr, N_NODES, H, z, emb, h);
    hipMemsetAsync(agg, 0, (size_t)N_NODES * H * sizeof(float), stream);

    const int edgeBlocks = 1280;   // 5 resident blocks/CU x 256 CUs (LDS 28.8KB limit)
    for (int l = 0; l < LAYERS; ++l) {
        if (attrp)
            edge_kernel<true, true><<<edgeBlocks, 256, 0, stream>>>(
                pattr, eattr, perm, esrc, edst, ew, Sp, Dp, Cp,
                w1t + (size_t)l * 128 * 64, mlp_b1 + (size_t)l * H,
                w2t + (size_t)l * 128 * 128, mlp_b2 + (size_t)l * H, x, agg);
        else if (idxp)
            edge_kernel<true, false><<<edgeBlocks, 256, 0, stream>>>(
                pattr, eattr, perm, esrc, edst, ew, Sp, Dp, Cp,
                w1t + (size_t)l * 128 * 64, mlp_b1 + (size_t)l * H,
                w2t + (size_t)l * 128 * 128, mlp_b2 + (size_t)l * H, x, agg);
        else
            edge_kernel<false, false><<<edgeBlocks, 256, 0, stream>>>(
                pattr, eattr, perm, esrc, edst, ew, Sp, Dp, Cp,
                w1t + (size_t)l * 128 * 64, mlp_b1 + (size_t)l * H,
                w2t + (size_t)l * 128 * 128, mlp_b2 + (size_t)l * H, x, agg);
        if (l < LAYERS - 1) {
            // tail + fused x_next = h_new @ cf_w1[l+1]; also re-zeros agg
            node_gemm2_mfma<true><<<dim3(rowTiles, 1), 256, 0, stream>>>(
                agg,
                nwhi + (size_t)(3 + l) * 16384, nwlo + (size_t)(3 + l) * 16384, cf_b2 + (size_t)l * H,
                nwhi + (size_t)(6 + l) * 16384, nwlo + (size_t)(6 + l) * 16384, lin_b + (size_t)l * H,
                nwhi + (size_t)(l + 1) * 16384, nwlo + (size_t)(l + 1) * 16384,
                h, x, N_NODES);
        } else {
            node_gemm2_mfma<false><<<dim3(rowTiles, 1), 256, 0, stream>>>(
                agg,
                nwhi + (size_t)(3 + l) * 16384, nwlo + (size_t)(3 + l) * 16384, cf_b2 + (size_t)l * H,
                nwhi + (size_t)(6 + l) * 16384, nwlo + (size_t)(6 + l) * 16384, lin_b + (size_t)l * H,
                nullptr, nullptr,
                h, nullptr, N_NODES);
        }
    }

    hipMemsetAsync(pooled, 0, (size_t)G_GRAPHS * 5 * H * sizeof(float), stream);
    node_gemm_mfma<F_BIAS | F_POOL><<<dim3(rowTiles, 5), 256, 0, stream>>>(
        h, nwhi + (size_t)9 * 16384, nwlo + (size_t)9 * 16384, ro_b1, pooled, batch, N_NODES, 5 * H,
        nullptr, nullptr, nullptr);
    final_out<<<G_GRAPHS, 128, 0, stream>>>(pooled, ro_w2, ro_b2, ro_w3, ro_b3, out);
}

// Round 10
// 1975.964 us; speedup vs baseline: 2.1137x; 2.1137x over previous
//
#include <hip/hip_runtime.h>
#include <math.h>

#define N_NODES 50000
#define N_EDGES 1000000
#define LAYERS  3
#define G_GRAPHS 512
#define H 128
#define NG 50
#define PI_F 3.14159265358979323846f
#define LOG2_F 0.6931471805599453f

typedef __attribute__((ext_vector_type(4))) float f32x4;
typedef __attribute__((ext_vector_type(8))) short short8;   // 8 bf16 = 4 VGPRs (MFMA A/B frag)

__device__ __forceinline__ float ssp(float v) {
    float t = __expf(-fabsf(v));
    return fmaxf(v, 0.0f) + __logf(1.0f + t) - LOG2_F;
}

__device__ __forceinline__ unsigned short f2bf(float f) {
    unsigned u = __float_as_uint(f);
    unsigned r = (u + 0x7fff + ((u >> 16) & 1)) >> 16;
    return (unsigned short)r;
}
__device__ __forceinline__ float bf2f(unsigned short h) {
    return __uint_as_float((unsigned)h << 16);
}

// -------------------- CSR build: sort edges by dst --------------------
__global__ __launch_bounds__(256) void hist_kernel(const int* __restrict__ edst,
                                                   int* __restrict__ cnt) {
    int e = blockIdx.x * 256 + threadIdx.x;
    if (e < N_EDGES) atomicAdd(&cnt[edst[e]], 1);
}

// single-block exclusive scan, shuffle-based
__global__ __launch_bounds__(1024) void scan_kernel(const int* __restrict__ cnt,
                                                    int* __restrict__ cur) {
    __shared__ int wsum[16];
    __shared__ int carry_s;
    int tid = threadIdx.x;
    int wid = tid >> 6, lane = tid & 63;
    if (tid == 0) carry_s = 0;
    __syncthreads();
    for (int base = 0; base < N_NODES; base += 1024) {
        int i = base + tid;
        int v = (i < N_NODES) ? cnt[i] : 0;
        int s = v;
#pragma unroll
        for (int d = 1; d < 64; d <<= 1) {
            int t = __shfl_up(s, d, 64);
            if (lane >= d) s += t;
        }
        if (lane == 63) wsum[wid] = s;
        __syncthreads();
        if (wid == 0) {
            int ws = (lane < 16) ? wsum[lane] : 0;
#pragma unroll
            for (int d = 1; d < 16; d <<= 1) {
                int t = __shfl_up(ws, d, 64);
                if (lane >= d) ws += t;
            }
            if (lane < 16) wsum[lane] = ws;
        }
        __syncthreads();
        int waveoff = (wid > 0) ? wsum[wid - 1] : 0;
        int carry = carry_s;
        if (i < N_NODES) cur[i] = carry + waveoff + s - v;
        __syncthreads();
        if (tid == 1023) carry_s = carry + wsum[15];
    }
}

// scatter + (optionally) fused meta permute: Sp/Dp/Cp written in CSR order directly
template <bool WRITEMETA>
__global__ __launch_bounds__(256) void scatter_kernel(const int* __restrict__ esrc,
                                                      const int* __restrict__ edst,
                                                      const float* __restrict__ ew,
                                                      int* __restrict__ cur,
                                                      int* __restrict__ perm,
                                                      int* __restrict__ Sp,
                                                      int* __restrict__ Dp,
                                                      float* __restrict__ Cp) {
    int e = blockIdx.x * 256 + threadIdx.x;
    if (e < N_EDGES) {
        int d = edst[e];
        int p = atomicAdd(&cur[d], 1);
        perm[p] = e;
        if (WRITEMETA) {
            Sp[p] = esrc[e];
            Dp[p] = d;
            Cp[p] = 0.5f * (cosf(ew[e] * (PI_F / 10.0f)) + 1.0f);
        }
    }
}

// pattr[pos][0..63] bf16 = eattr[perm[pos]][0..49] (zero-padded). 8 threads/edge.
__global__ __launch_bounds__(256) void prep_attr(const int* __restrict__ perm,
                                                 const float* __restrict__ eattr,
                                                 unsigned short* __restrict__ pattr) {
    int t = blockIdx.x * 256 + threadIdx.x;
    int pos = t >> 3, kq = t & 7;
    if (pos >= N_EDGES) return;
    int ge = perm[pos];
    int k0 = kq * 8;
    float v[8] = {0.f, 0.f, 0.f, 0.f, 0.f, 0.f, 0.f, 0.f};
    const float* row = eattr + (size_t)ge * NG;
    if (k0 + 8 <= NG) {
#pragma unroll
        for (int q = 0; q < 4; ++q) {
            float2 a = *(const float2*)(row + k0 + 2 * q);
            v[2 * q] = a.x; v[2 * q + 1] = a.y;
        }
    } else if (k0 < NG) {            // k0 == 48
        float2 a = *(const float2*)(row + k0);
        v[0] = a.x; v[1] = a.y;
    }
    uint4 wv;
    wv.x = (unsigned)f2bf(v[0]) | ((unsigned)f2bf(v[1]) << 16);
    wv.y = (unsigned)f2bf(v[2]) | ((unsigned)f2bf(v[3]) << 16);
    wv.z = (unsigned)f2bf(v[4]) | ((unsigned)f2bf(v[5]) << 16);
    wv.w = (unsigned)f2bf(v[6]) | ((unsigned)f2bf(v[7]) << 16);
    *(uint4*)(pattr + (size_t)pos * 64 + k0) = wv;
}

// -------------------- filter weight pre-convert (single bf16) --------------------
__global__ __launch_bounds__(256) void conv_w(const float* __restrict__ mlp_w1,
                                              const float* __restrict__ mlp_w2,
                                              unsigned short* __restrict__ w1t,
                                              unsigned short* __restrict__ w2t) {
    int idx = blockIdx.x * 256 + threadIdx.x;
    const int n1 = LAYERS * 128 * 64;
    if (idx < n1) {
        int l = idx / (128 * 64);
        int rem = idx - l * 128 * 64;
        int col = rem >> 6, k = rem & 63;
        float v = (k < NG) ? mlp_w1[(size_t)l * NG * H + (size_t)k * H + col] : 0.f;
        w1t[idx] = f2bf(v);
        return;
    }
    int idx2 = idx - n1;
    if (idx2 < LAYERS * 128 * 128) {
        int l = idx2 / (128 * 128);
        int rem = idx2 - l * 128 * 128;
        int col = rem >> 7, k = rem & 127;
        w2t[idx2] = f2bf(mlp_w2[(size_t)l * H * H + (size_t)k * H + col]);
    }
}

// -------------------- node weight pre-convert, ALL matrices in one launch --------------------
// nw layout (16384-elem slots): [0..2]=cf_w1[l], [3..5]=cf_w2[l], [6..8]=lin_w[l], [9..]=ro_w1 (640x128)
__global__ __launch_bounds__(256) void conv_nodew_all(const float* __restrict__ cf_w1,
                                                      const float* __restrict__ cf_w2,
                                                      const float* __restrict__ lin_w,
                                                      const float* __restrict__ ro_w1,
                                                      unsigned short* __restrict__ hi,
                                                      unsigned short* __restrict__ lo) {
    int idx = blockIdx.x * 256 + threadIdx.x;
    const int SQ = LAYERS * 128 * 128;   // 49152
    float v; int dst;
    if (idx < 3 * SQ) {
        int fam = idx / SQ, rem = idx - fam * SQ;
        int l = rem / 16384, r2 = rem & 16383;
        int col = r2 >> 7, k = r2 & 127;
        const float* src = (fam == 0) ? cf_w1 : ((fam == 1) ? cf_w2 : lin_w);
        v = src[(size_t)l * 16384 + (size_t)k * 128 + col];
        dst = (fam * 3 + l) * 16384 + r2;
    } else {
        int j = idx - 3 * SQ;
        if (j >= 640 * 128) return;
        int col = j >> 7, k = j & 127;
        v = ro_w1[(size_t)k * 640 + col];
        dst = 3 * SQ + j;
    }
    unsigned short h16 = f2bf(v);
    hi[dst] = h16;
    lo[dst] = f2bf(v - bf2f(h16));
}

#define F_BIAS 1
#define F_POOL 8
#define F_EMB  16

// -------------------- MFMA node GEMM (split-bf16) --------------------
// F_EMB: A-row = relu(emb[z[row]]) and h is also written (fused init_h + x0).
template <int FLAGS>
__global__ __launch_bounds__(256, 4) void node_gemm_mfma(const float* __restrict__ A,
                                                         const unsigned short* __restrict__ BtHi,
                                                         const unsigned short* __restrict__ BtLo,
                                                         const float* __restrict__ bias,
                                                         float* __restrict__ Out,
                                                         const int* __restrict__ batch,
                                                         int nRows, int NC,
                                                         const int* __restrict__ z,
                                                         const float* __restrict__ emb,
                                                         float* __restrict__ hOut) {
    __shared__ __align__(16) char ldsHi[64 * 256];
    __shared__ __align__(16) char ldsLo[64 * 256];
    int tid = threadIdx.x;
    int rowBase = blockIdx.x * 64;
    int colOff = blockIdx.y * 128;
    int rlim = nRows - rowBase; if (rlim > 64) rlim = 64;

    for (int idx = tid; idx < 64 * 32; idx += 256) {
        int r = idx >> 5, q = idx & 31;
        float4 v = make_float4(0.f, 0.f, 0.f, 0.f);
        if (r < rlim) {
            if (FLAGS & F_EMB) {
                int zr = z[rowBase + r];
                v = *(const float4*)(emb + (size_t)zr * H + q * 4);
                v.x = fmaxf(v.x, 0.f); v.y = fmaxf(v.y, 0.f);
                v.z = fmaxf(v.z, 0.f); v.w = fmaxf(v.w, 0.f);
                *(float4*)(hOut + (size_t)(rowBase + r) * H + q * 4) = v;
            } else {
                v = *(const float4*)(A + (size_t)(rowBase + r) * H + q * 4);
            }
        }
        unsigned short h0 = f2bf(v.x), h1 = f2bf(v.y), h2 = f2bf(v.z), h3 = f2bf(v.w);
        unsigned short l0 = f2bf(v.x - bf2f(h0)), l1 = f2bf(v.y - bf2f(h1));
        unsigned short l2 = f2bf(v.z - bf2f(h2)), l3 = f2bf(v.w - bf2f(h3));
        int byte = (r << 8) + (q << 3);
        byte ^= (r & 7) << 4;
        *(uint2*)(ldsHi + byte) = make_uint2((unsigned)h0 | ((unsigned)h1 << 16),
                                             (unsigned)h2 | ((unsigned)h3 << 16));
        *(uint2*)(ldsLo + byte) = make_uint2((unsigned)l0 | ((unsigned)l1 << 16),
                                             (unsigned)l2 | ((unsigned)l3 << 16));
    }
    __syncthreads();

    int w = tid >> 6, lane = tid & 63;
    int lg = lane >> 4, cg = lane & 15;
    int swA = (cg & 7) << 4;

    f32x4 acc[4][2];
#pragma unroll
    for (int n = 0; n < 2; ++n) {
        float b = (FLAGS & F_BIAS) ? bias[colOff + w * 32 + n * 16 + cg] : 0.f;
        f32x4 t = {b, b, b, b};
#pragma unroll
        for (int m = 0; m < 4; ++m) acc[m][n] = t;
    }

#pragma unroll
    for (int kc = 0; kc < 4; ++kc) {
        short8 aHi[4], aLo[4], bHi[2], bLo[2];
#pragma unroll
        for (int m = 0; m < 4; ++m) {
            int byte = ((m * 16 + cg) << 8) + ((kc * 32 + lg * 8) << 1);
            aHi[m] = *(short8*)(ldsHi + (byte ^ swA));
            aLo[m] = *(short8*)(ldsLo + (byte ^ swA));
        }
#pragma unroll
        for (int n = 0; n < 2; ++n) {
            size_t off = (size_t)(colOff + w * 32 + n * 16 + cg) * 128 + kc * 32 + lg * 8;
            bHi[n] = *(const short8*)(BtHi + off);
            bLo[n] = *(const short8*)(BtLo + off);
        }
#pragma unroll
        for (int m = 0; m < 4; ++m)
#pragma unroll
            for (int n = 0; n < 2; ++n) {
                acc[m][n] = __builtin_amdgcn_mfma_f32_16x16x32_bf16(aHi[m], bHi[n], acc[m][n], 0, 0, 0);
                acc[m][n] = __builtin_amdgcn_mfma_f32_16x16x32_bf16(aLo[m], bHi[n], acc[m][n], 0, 0, 0);
                acc[m][n] = __builtin_amdgcn_mfma_f32_16x16x32_bf16(aHi[m], bLo[n], acc[m][n], 0, 0, 0);
            }
    }

    if (FLAGS & F_POOL) {
        int cur = -1;
        float s[2] = {0.f, 0.f};
#pragma unroll
        for (int m = 0; m < 4; ++m) {
#pragma unroll
            for (int i = 0; i < 4; ++i) {
                int row = m * 16 + lg * 4 + i;
                int b = (row < rlim) ? batch[rowBase + row] : -1;
                if (b != cur) {
                    if (cur >= 0) {
#pragma unroll
                        for (int n = 0; n < 2; ++n)
                            unsafeAtomicAdd(Out + (size_t)cur * NC + colOff + w * 32 + n * 16 + cg, s[n]);
                    }
                    cur = b;
                    s[0] = 0.f; s[1] = 0.f;
                }
                if (b >= 0) {
#pragma unroll
                    for (int n = 0; n < 2; ++n) s[n] += ssp(acc[m][n][i]);
                }
            }
        }
        if (cur >= 0) {
#pragma unroll
            for (int n = 0; n < 2; ++n)
                unsafeAtomicAdd(Out + (size_t)cur * NC + colOff + w * 32 + n * 16 + cg, s[n]);
        }
    } else {
#pragma unroll
        for (int m = 0; m < 4; ++m)
#pragma unroll
            for (int i = 0; i < 4; ++i) {
                int row = m * 16 + lg * 4 + i;
                if (row < rlim) {
#pragma unroll
                    for (int n = 0; n < 2; ++n)
                        Out[(size_t)(rowBase + row) * NC + colOff + w * 32 + n * 16 + cg] = acc[m][n][i];
                }
            }
    }
}

// -------------------- fused per-layer tail: h += ssp(agg@W2+b2)@WL+bl ; optional x_next = h@W1n --------------------
// Also re-zeroes agg while staging it (removes per-layer memset).
template <bool XNEXT>
__global__ __launch_bounds__(256, 4) void node_gemm2_mfma(float* __restrict__ Agg,
                                                          const unsigned short* __restrict__ W2hi,
                                                          const unsigned short* __restrict__ W2lo,
                                                          const float* __restrict__ b2,
                                                          const unsigned short* __restrict__ WLhi,
                                                          const unsigned short* __restrict__ WLlo,
                                                          const float* __restrict__ bl,
                                                          const unsigned short* __restrict__ W1nhi,
                                                          const unsigned short* __restrict__ W1nlo,
                                                          float* __restrict__ Hio,
                                                          float* __restrict__ xout,
                                                          int nRows) {
    __shared__ __align__(16) char ldsHi[64 * 256];
    __shared__ __align__(16) char ldsLo[64 * 256];
    int tid = threadIdx.x;
    int rowBase = blockIdx.x * 64;
    int rlim = nRows - rowBase; if (rlim > 64) rlim = 64;

    for (int idx = tid; idx < 64 * 32; idx += 256) {
        int r = idx >> 5, q = idx & 31;
        float4 v = make_float4(0.f, 0.f, 0.f, 0.f);
        if (r < rlim) {
            float* p = Agg + (size_t)(rowBase + r) * H + q * 4;
            v = *(float4*)p;
            *(float4*)p = make_float4(0.f, 0.f, 0.f, 0.f);   // zero agg for next layer
        }
        unsigned short h0 = f2bf(v.x), h1 = f2bf(v.y), h2 = f2bf(v.z), h3 = f2bf(v.w);
        unsigned short l0 = f2bf(v.x - bf2f(h0)), l1 = f2bf(v.y - bf2f(h1));
        unsigned short l2 = f2bf(v.z - bf2f(h2)), l3 = f2bf(v.w - bf2f(h3));
        int byte = (r << 8) + (q << 3);
        byte ^= (r & 7) << 4;
        *(uint2*)(ldsHi + byte) = make_uint2((unsigned)h0 | ((unsigned)h1 << 16),
                                             (unsigned)h2 | ((unsigned)h3 << 16));
        *(uint2*)(ldsLo + byte) = make_uint2((unsigned)l0 | ((unsigned)l1 << 16),
                                             (unsigned)l2 | ((unsigned)l3 << 16));
    }
    __syncthreads();

    int w = tid >> 6, lane = tid & 63;
    int lg = lane >> 4, cg = lane & 15;
    int swA = (cg & 7) << 4;

    // ---- GEMM-A: x1 = agg @ W2 + b2 ----
    f32x4 acc[4][2];
#pragma unroll
    for (int n = 0; n < 2; ++n) {
        float b = b2[w * 32 + n * 16 + cg];
        f32x4 t = {b, b, b, b};
#pragma unroll
        for (int m = 0; m < 4; ++m) acc[m][n] = t;
    }
#pragma unroll
    for (int kc = 0; kc < 4; ++kc) {
        short8 aHi[4], aLo[4], bHi[2], bLo[2];
#pragma unroll
        for (int m = 0; m < 4; ++m) {
            int byte = ((m * 16 + cg) << 8) + ((kc * 32 + lg * 8) << 1);
            aHi[m] = *(short8*)(ldsHi + (byte ^ swA));
            aLo[m] = *(short8*)(ldsLo + (byte ^ swA));
        }
#pragma unroll
        for (int n = 0; n < 2; ++n) {
            size_t off = (size_t)(w * 32 + n * 16 + cg) * 128 + kc * 32 + lg * 8;
            bHi[n] = *(const short8*)(W2hi + off);
            bLo[n] = *(const short8*)(W2lo + off);
        }
#pragma unroll
        for (int m = 0; m < 4; ++m)
#pragma unroll
            for (int n = 0; n < 2; ++n) {
                acc[m][n] = __builtin_amdgcn_mfma_f32_16x16x32_bf16(aHi[m], bHi[n], acc[m][n], 0, 0, 0);
                acc[m][n] = __builtin_amdgcn_mfma_f32_16x16x32_bf16(aLo[m], bHi[n], acc[m][n], 0, 0, 0);
                acc[m][n] = __builtin_amdgcn_mfma_f32_16x16x32_bf16(aHi[m], bLo[n], acc[m][n], 0, 0, 0);
            }
    }
    __syncthreads();

    // ---- write ssp(x1) back to LDS as split-bf16 [row][col] ----
#pragma unroll
    for (int m = 0; m < 4; ++m)
#pragma unroll
        for (int n = 0; n < 2; ++n)
#pragma unroll
            for (int i = 0; i < 4; ++i) {
                int row = m * 16 + lg * 4 + i;
                int col = w * 32 + n * 16 + cg;
                float v = ssp(acc[m][n][i]);
                unsigned short hh = f2bf(v);
                unsigned short ll = f2bf(v - bf2f(hh));
                int byte = (row << 8) + (col << 1);
                byte ^= (row & 7) << 4;
                *(unsigned short*)(ldsHi + byte) = hh;
                *(unsigned short*)(ldsLo + byte) = ll;
            }
    __syncthreads();

    // ---- GEMM-B: dh = x1s @ WL + bl ----
    f32x4 acc2[4][2];
#pragma unroll
    for (int n = 0; n < 2; ++n) {
        float b = bl[w * 32 + n * 16 + cg];
        f32x4 t = {b, b, b, b};
#pragma unroll
        for (int m = 0; m < 4; ++m) acc2[m][n] = t;
    }
#pragma unroll
    for (int kc = 0; kc < 4; ++kc) {
        short8 aHi[4], aLo[4], bHi[2], bLo[2];
#pragma unroll
        for (int m = 0; m < 4; ++m) {
            int byte = ((m * 16 + cg) << 8) + ((kc * 32 + lg * 8) << 1);
            aHi[m] = *(short8*)(ldsHi + (byte ^ swA));
            aLo[m] = *(short8*)(ldsLo + (byte ^ swA));
        }
#pragma unroll
        for (int n = 0; n < 2; ++n) {
            size_t off = (size_t)(w * 32 + n * 16 + cg) * 128 + kc * 32 + lg * 8;
            bHi[n] = *(const short8*)(WLhi + off);
            bLo[n] = *(const short8*)(WLlo + off);
        }
#pragma unroll
        for (int m = 0; m < 4; ++m)
#pragma unroll
            for (int n = 0; n < 2; ++n) {
                acc2[m][n] = __builtin_amdgcn_mfma_f32_16x16x32_bf16(aHi[m], bHi[n], acc2[m][n], 0, 0, 0);
                acc2[m][n] = __builtin_amdgcn_mfma_f32_16x16x32_bf16(aLo[m], bHi[n], acc2[m][n], 0, 0, 0);
                acc2[m][n] = __builtin_amdgcn_mfma_f32_16x16x32_bf16(aHi[m], bLo[n], acc2[m][n], 0, 0, 0);
            }
    }

    if (XNEXT) {
        __syncthreads();   // all waves done with GEMM-B's LDS reads before restage
        // ---- h_new = h + dh -> global AND split-LDS for GEMM-C ----
#pragma unroll
        for (int m = 0; m < 4; ++m)
#pragma unroll
            for (int n = 0; n < 2; ++n)
#pragma unroll
                for (int i = 0; i < 4; ++i) {
                    int row = m * 16 + lg * 4 + i;
                    int col = w * 32 + n * 16 + cg;
                    float hnew = 0.f;
                    if (row < rlim) {
                        float* p = Hio + (size_t)(rowBase + row) * H + col;
                        hnew = *p + acc2[m][n][i];
                        *p = hnew;
                    }
                    unsigned short hh = f2bf(hnew);
                    unsigned short ll = f2bf(hnew - bf2f(hh));
                    int byte = (row << 8) + (col << 1);
                    byte ^= (row & 7) << 4;
                    *(unsigned short*)(ldsHi + byte) = hh;
                    *(unsigned short*)(ldsLo + byte) = ll;
                }
        __syncthreads();

        // ---- GEMM-C: x_next = h_new @ W1n (no bias) ----
        f32x4 acc3[4][2];
#pragma unroll
        for (int n = 0; n < 2; ++n) {
            f32x4 t = {0.f, 0.f, 0.f, 0.f};
#pragma unroll
            for (int m = 0; m < 4; ++m) acc3[m][n] = t;
        }
#pragma unroll
        for (int kc = 0; kc < 4; ++kc) {
            short8 aHi[4], aLo[4], bHi[2], bLo[2];
#pragma unroll
            for (int m = 0; m < 4; ++m) {
                int byte = ((m * 16 + cg) << 8) + ((kc * 32 + lg * 8) << 1);
                aHi[m] = *(short8*)(ldsHi + (byte ^ swA));
                aLo[m] = *(short8*)(ldsLo + (byte ^ swA));
            }
#pragma unroll
            for (int n = 0; n < 2; ++n) {
                size_t off = (size_t)(w * 32 + n * 16 + cg) * 128 + kc * 32 + lg * 8;
                bHi[n] = *(const short8*)(W1nhi + off);
                bLo[n] = *(const short8*)(W1nlo + off);
            }
#pragma unroll
            for (int m = 0; m < 4; ++m)
#pragma unroll
                for (int n = 0; n < 2; ++n) {
                    acc3[m][n] = __builtin_amdgcn_mfma_f32_16x16x32_bf16(aHi[m], bHi[n], acc3[m][n], 0, 0, 0);
                    acc3[m][n] = __builtin_amdgcn_mfma_f32_16x16x32_bf16(aLo[m], bHi[n], acc3[m][n], 0, 0, 0);
                    acc3[m][n] = __builtin_amdgcn_mfma_f32_16x16x32_bf16(aHi[m], bLo[n], acc3[m][n], 0, 0, 0);
                }
        }
#pragma unroll
        for (int m = 0; m < 4; ++m)
#pragma unroll
            for (int i = 0; i < 4; ++i) {
                int row = m * 16 + lg * 4 + i;
                if (row < rlim) {
#pragma unroll
                    for (int n = 0; n < 2; ++n)
                        xout[(size_t)(rowBase + row) * H + w * 32 + n * 16 + cg] = acc3[m][n][i];
                }
            }
    } else {
#pragma unroll
        for (int m = 0; m < 4; ++m)
#pragma unroll
            for (int i = 0; i < 4; ++i) {
                int row = m * 16 + lg * 4 + i;
                if (row < rlim) {
#pragma unroll
                    for (int n = 0; n < 2; ++n) {
                        float* p = Hio + (size_t)(rowBase + row) * H + w * 32 + n * 16 + cg;
                        *p += acc2[m][n][i];
                    }
                }
            }
    }
}

// -------------------- fused edge kernel: round-4 v3b VERBATIM (best measured: 425us) --------------------
// Consolidation round: R5-R9 restructurings all lost to spill / duplicated compute /
// atomic write-amplification / persistent-loop spill. This is the exact round-4 kernel.
template <bool IDXP, bool ATTRP>
__global__ __launch_bounds__(256, 5) void edge_kernel(
        const unsigned short* __restrict__ pattr,
        const float* __restrict__ eattr,
        const int* __restrict__ perm,
        const int* __restrict__ esrc,
        const int* __restrict__ edst,
        const float* __restrict__ ew,
        const int* __restrict__ Sp,
        const int* __restrict__ Dp,
        const float* __restrict__ Cp,
        const unsigned short* __restrict__ W1t,
        const float* __restrict__ b1,
        const unsigned short* __restrict__ W2t,
        const float* __restrict__ b2,
        const float* __restrict__ x,
        float* __restrict__ agg) {
    // LDS map (bytes):
    // [0,     8192)  attr bf16 [64 rows][64 k], xor-swizzled
    // [8192, 24576)  T bf16 [64][128], xor-swizzled
    // [24576,28800)  accT fp32 [8 runs][132]
    // [28800,28832)  RunDst[8]
    __shared__ __align__(16) char lds[28832];
    float* accT = (float*)(lds + 24576);
    int* RunDst = (int*)(lds + 28800);

    int tid = threadIdx.x;
    int e0 = blockIdx.x * 64;
    int w = tid >> 6, lane = tid & 63;

    // zero accT (completes before barrier1; region disjoint from attr/T)
    for (int i = tid; i < 8 * 132; i += 256) accT[i] = 0.f;

    // per-lane meta for block-edge l = lane
    int ge = 0;
    if (!ATTRP || !IDXP) ge = perm[e0 + lane];
    int S, D; float C;
    if (IDXP) {
        S = Sp[e0 + lane]; D = Dp[e0 + lane]; C = Cp[e0 + lane];
    } else {
        S = esrc[ge]; D = edst[ge];
        C = 0.5f * (cosf(ew[ge] * (PI_F / 10.0f)) + 1.0f);
    }
    int prevd = -1, nextd = -1;
    if (e0 > 0)            prevd = IDXP ? Dp[e0 - 1]  : edst[perm[e0 - 1]];
    if (e0 + 64 < N_EDGES) nextd = IDXP ? Dp[e0 + 64] : edst[perm[e0 + 64]];

    // ---- stage attr rows for THIS wave: rows w*16 .. w*16+15 (wave-local) ----
    if (ATTRP) {
        // 16 rows x 8 chunks(16B) = 128 chunk-loads; 64 lanes x 2 halves.
#pragma unroll
        for (int half = 0; half < 2; ++half) {
            int idx2 = lane + half * 64;
            int row = w * 16 + (idx2 >> 3);
            int q = idx2 & 7;
            uint4 v = *(const uint4*)(pattr + (((size_t)(e0 + row)) << 6) + q * 8);
            int byte = (row << 7) + (q << 4);
            byte ^= (row & 7) << 4;
            *(uint4*)(lds + byte) = v;
        }
    } else {
        int row = w * 16 + (lane >> 2);
        int grow = __shfl(ge, row);
        int jbase = (lane & 3) * 8;
#pragma unroll
        for (int j = 0; j < 8; ++j) {
            int k2 = jbase + j;
            float a0 = 0.f, a1 = 0.f;
            if (k2 < 25) {
                float2 t = *(const float2*)(eattr + (size_t)grow * NG + 2 * k2);
                a0 = t.x; a1 = t.y;
            }
            unsigned p = (unsigned)f2bf(a0) | ((unsigned)f2bf(a1) << 16);
            int byte = (row << 7) + (k2 << 2);
            byte ^= (row & 7) << 4;
            *(unsigned*)(lds + byte) = p;
        }
    }

    int lg = lane >> 4, cg = lane & 15;
    int eB = w * 16 + cg;
    int swz = (eB & 7) << 4;
    int le0 = w * 16 + lg * 4;

    // ---- GEMM1': D[Tcol][edge] = W1t @ attr^T + b1 (wave-local LDS, in-order DS) ----
    f32x4 acc1[8];
#pragma unroll
    for (int mt = 0; mt < 8; ++mt)
        acc1[mt] = *(const f32x4*)(b1 + mt * 16 + lg * 4);
#pragma unroll
    for (int kc = 0; kc < 2; ++kc) {
        int byteB = (eB << 7) + (kc << 6) + (lg << 4);
        short8 bfrag = *(short8*)(lds + (byteB ^ swz));
#pragma unroll
        for (int mt = 0; mt < 8; ++mt) {
            short8 afrag = *(const short8*)(W1t + ((mt * 16 + cg) << 6) + (kc << 5) + (lg << 3));
            acc1[mt] = __builtin_amdgcn_mfma_f32_16x16x32_bf16(afrag, bfrag, acc1[mt], 0, 0, 0);
        }
    }
    // T = ssp(acc1) -> LDS bf16 (wave-local rows; no barrier)
#pragma unroll
    for (int mt = 0; mt < 8; ++mt) {
        f32x4 v = acc1[mt];
        unsigned p0 = (unsigned)f2bf(ssp(v[0])) | ((unsigned)f2bf(ssp(v[1])) << 16);
        unsigned p1 = (unsigned)f2bf(ssp(v[2])) | ((unsigned)f2bf(ssp(v[3])) << 16);
        int byte = 8192 + (eB << 8) + (mt << 5) + (lg << 3);
        *(uint2*)(lds + (byte ^ swz)) = make_uint2(p0, p1);
    }

    // ---- GEMM2: Wf[edge][col] = T @ W2t^T + b2 (wave-local reads) ----
    f32x4 acc2[8];
#pragma unroll
    for (int n = 0; n < 8; ++n) {
        float bb = b2[n * 16 + cg];
        f32x4 t = {bb, bb, bb, bb};
        acc2[n] = t;
    }
#pragma unroll
    for (int kc = 0; kc < 4; ++kc) {
        int byteA = 8192 + (eB << 8) + (kc << 6) + (lg << 4);
        short8 afrag = *(short8*)(lds + (byteA ^ swz));
#pragma unroll
        for (int n = 0; n < 8; ++n) {
            short8 bfrag = *(const short8*)(W2t + ((n * 16 + cg) << 7) + (kc << 5) + (lg << 3));
            acc2[n] = __builtin_amdgcn_mfma_f32_16x16x32_bf16(afrag, bfrag, acc2[n], 0, 0, 0);
        }
    }

    // ---- x prefetch (vmcnt stays in flight across barrier1) ----
    float xv[4][8];
#pragma unroll
    for (int i = 0; i < 4; ++i) {
        int sle = __shfl(S, le0 + i);
        const float* xrow = x + (size_t)sle * H + cg;
#pragma unroll
        for (int n = 0; n < 8; ++n) xv[i][n] = xrow[n * 16];
    }

    // ---- run-id scan in registers (redundant per wave; no LDS) ----
    int dprev = __shfl_up(D, 1, 64);
    int flag = (lane > 0 && D != dprev) ? 1 : 0;
    int rid = flag;
#pragma unroll
    for (int s2 = 1; s2 < 64; s2 <<= 1) {
        int o = __shfl_up(rid, s2, 64);
        if (lane >= s2) rid += o;
    }
    int nruns = __shfl(rid, 63) + 1;
    if (w == 0 && (lane == 0 || flag) && rid < 8) RunDst[rid] = D;

    // barrier1: accT zero + RunDst visible to all; vmcnt (x gathers) NOT drained
    asm volatile("s_waitcnt lgkmcnt(0)" ::: "memory");
    __builtin_amdgcn_s_barrier();
    asm volatile("" ::: "memory");

    // ---- per-run accumulation: LDS atomics (runs < 8) or global atomics (overflow) ----
    int curR = -1, curD = 0;
    float part[8];
#pragma unroll
    for (int i = 0; i < 4; ++i) {
        int le = le0 + i;
        int r  = __shfl(rid, le);
        int dd = __shfl(D, le);
        float cf = __shfl(C, le);
        float m[8];
#pragma unroll
        for (int n = 0; n < 8; ++n) m[n] = xv[i][n] * acc2[n][i] * cf;
        if (r != curR) {
            if (curR >= 0) {
                if (curR < 8) {
#pragma unroll
                    for (int n = 0; n < 8; ++n)
                        atomicAdd(accT + curR * 132 + n * 16 + cg, part[n]);
                } else {
#pragma unroll
                    for (int n = 0; n < 8; ++n)
                        unsafeAtomicAdd(agg + (size_t)curD * H + n * 16 + cg, part[n]);
                }
            }
            curR = r; curD = dd;
#pragma unroll
            for (int n = 0; n < 8; ++n) part[n] = m[n];
        } else {
#pragma unroll
            for (int n = 0; n < 8; ++n) part[n] += m[n];
        }
    }
    if (curR < 8) {
#pragma unroll
        for (int n = 0; n < 8; ++n)
            atomicAdd(accT + curR * 132 + n * 16 + cg, part[n]);
    } else {
#pragma unroll
        for (int n = 0; n < 8; ++n)
            unsafeAtomicAdd(agg + (size_t)curD * H + n * 16 + cg, part[n]);
    }

    // barrier2: all LDS atomics done
    asm volatile("s_waitcnt lgkmcnt(0)" ::: "memory");
    __builtin_amdgcn_s_barrier();
    asm volatile("" ::: "memory");

    // ---- store complete runs; boundary-shared runs via global atomic ----
    int nstore = (nruns < 8) ? nruns : 8;
    for (int idx = tid; idx < nstore * H; idx += 256) {
        int r = idx >> 7, c = idx & 127;
        float v = accT[r * 132 + c];
        int d = RunDst[r];
        bool shared_run = (r == 0 && d == prevd) || (r == nruns - 1 && d == nextd);
        float* p = agg + (size_t)d * H + c;
        if (shared_run) unsafeAtomicAdd(p, v);
        else *p = v;
    }
}

// -------------------- out = ssp(pooled@ro_w2 + b2) @ ro_w3 + b3 --------------------
__global__ __launch_bounds__(128) void final_out(const float* __restrict__ pooled,
                                                 const float* __restrict__ ro_w2,
                                                 const float* __restrict__ ro_b2,
                                                 const float* __restrict__ ro_w3,
                                                 const float* __restrict__ ro_b3,
                                                 float* __restrict__ out) {
    int g = blockIdx.x;
    int c = threadIdx.x;
    float acc = ro_b2[c];
    const float* pr = pooled + (size_t)g * (5 * H);
    for (int k = 0; k < 5 * H; ++k) acc = fmaf(pr[k], ro_w2[(size_t)k * H + c], acc);
    float v = ssp(acc) * ro_w3[c];
    __shared__ float red[128];
    red[c] = v;
    __syncthreads();
    for (int s = 64; s > 0; s >>= 1) {
        if (c < s) red[c] += red[c + s];
        __syncthreads();
    }
    if (c == 0) out[g] = red[0] + ro_b3[0];
}

extern "C" void kernel_launch(void* const* d_in, const int* in_sizes, int n_in,
                              void* d_out, int out_size, void* d_ws, size_t ws_size,
                              hipStream_t stream) {
    const int* z     = (const int*)d_in[0];
    const int* esrc  = (const int*)d_in[1];
    const int* edst  = (const int*)d_in[2];
    const int* batch = (const int*)d_in[3];
    const float* ew    = (const float*)d_in[5];
    const float* eattr = (const float*)d_in[6];
    const float* emb   = (const float*)d_in[7];
    const float* mlp_w1 = (const float*)d_in[8];
    const float* mlp_b1 = (const float*)d_in[9];
    const float* mlp_w2 = (const float*)d_in[10];
    const float* mlp_b2 = (const float*)d_in[11];
    const float* cf_w1  = (const float*)d_in[12];
    const float* cf_w2  = (const float*)d_in[13];
    const float* cf_b2  = (const float*)d_in[14];
    const float* lin_w  = (const float*)d_in[15];
    const float* lin_b  = (const float*)d_in[16];
    const float* ro_w1  = (const float*)d_in[17];
    const float* ro_b1  = (const float*)d_in[18];
    const float* ro_w2  = (const float*)d_in[19];
    const float* ro_b2  = (const float*)d_in[20];
    const float* ro_w3  = (const float*)d_in[21];
    const float* ro_b3  = (const float*)d_in[22];
    float* out = (float*)d_out;

    char* wp = (char*)d_ws;
    auto alloc = [&](size_t bytes) {
        char* p = wp;
        wp += (bytes + 255) & ~(size_t)255;
        return p;
    };
    float* h      = (float*)alloc((size_t)N_NODES * H * 4);
    float* x      = (float*)alloc((size_t)N_NODES * H * 4);
    float* agg    = (float*)alloc((size_t)N_NODES * H * 4);
    float* pooled = (float*)alloc((size_t)G_GRAPHS * 5 * H * 4);
    int*   cnt    = (int*)alloc(N_NODES * 4);
    int*   cur    = (int*)alloc(N_NODES * 4);
    int*   perm   = (int*)alloc((size_t)N_EDGES * 4);
    unsigned short* w1t  = (unsigned short*)alloc((size_t)LAYERS * 128 * 64 * 2);
    unsigned short* w2t  = (unsigned short*)alloc((size_t)LAYERS * 128 * 128 * 2);
    unsigned short* nwhi = (unsigned short*)alloc((size_t)(9 * 16384 + 640 * 128) * 2);
    unsigned short* nwlo = (unsigned short*)alloc((size_t)(9 * 16384 + 640 * 128) * 2);
    int*   Sp = (int*)alloc((size_t)N_EDGES * 4);
    int*   Dp = (int*)alloc((size_t)N_EDGES * 4);
    float* Cp = (float*)alloc((size_t)N_EDGES * 4);
    size_t used_idx = (size_t)(wp - (char*)d_ws);
    unsigned short* pattr = (unsigned short*)alloc((size_t)N_EDGES * 64 * 2);
    size_t used_attr = (size_t)(wp - (char*)d_ws);

    bool idxp  = ws_size >= used_idx;
    bool attrp = ws_size >= used_attr;

    conv_w<<<(LAYERS * 128 * 64 + LAYERS * 128 * 128 + 255) / 256, 256, 0, stream>>>(
        mlp_w1, mlp_w2, w1t, w2t);
    conv_nodew_all<<<(3 * LAYERS * 128 * 128 + 640 * 128 + 255) / 256, 256, 0, stream>>>(
        cf_w1, cf_w2, lin_w, ro_w1, nwhi, nwlo);

    hipMemsetAsync(cnt, 0, N_NODES * sizeof(int), stream);
    hist_kernel<<<(N_EDGES + 255) / 256, 256, 0, stream>>>(edst, cnt);
    scan_kernel<<<1, 1024, 0, stream>>>(cnt, cur);
    if (idxp)
        scatter_kernel<true><<<(N_EDGES + 255) / 256, 256, 0, stream>>>(
            esrc, edst, ew, cur, perm, Sp, Dp, Cp);
    else
        scatter_kernel<false><<<(N_EDGES + 255) / 256, 256, 0, stream>>>(
            esrc, edst, ew, cur, perm, Sp, Dp, Cp);
    if (attrp)
        prep_attr<<<(N_EDGES * 8 + 255) / 256, 256, 0, stream>>>(perm, eattr, pattr);

    int rowTiles = (N_NODES + 63) / 64;  // 782

    // fused: h = relu(emb[z]); x = h @ cf_w1[0]
    node_gemm_mfma<F_EMB><<<dim3(rowTiles, 1), 256, 0, stream>>>(
        nullptr, nwhi, nwlo, nullptr, x, nullptr, N_NODES, H, z, emb, h);
    hipMemsetAsync(agg, 0, (size_t)N_NODES * H * sizeof(float), stream);

    for (int l = 0; l < LAYERS; ++l) {
        if (attrp)
            edge_kernel<true, true><<<N_EDGES / 64, 256, 0, stream>>>(
                pattr, eattr, perm, esrc, edst, ew, Sp, Dp, Cp,
                w1t + (size_t)l * 128 * 64, mlp_b1 + (size_t)l * H,
                w2t + (size_t)l * 128 * 128, mlp_b2 + (size_t)l * H, x, agg);
        else if (idxp)
            edge_kernel<true, false><<<N_EDGES / 64, 256, 0, stream>>>(
                pattr, eattr, perm, esrc, edst, ew, Sp, Dp, Cp,
                w1t + (size_t)l * 128 * 64, mlp_b1 + (size_t)l * H,
                w2t + (size_t)l * 128 * 128, mlp_b2 + (size_t)l * H, x, agg);
        else
            edge_kernel<false, false><<<N_EDGES / 64, 256, 0, stream>>>(
                pattr, eattr, perm, esrc, edst, ew, Sp, Dp, Cp,
                w1t + (size_t)l * 128 * 64, mlp_b1 + (size_t)l * H,
                w2t + (size_t)l * 128 * 128, mlp_b2 + (size_t)l * H, x, agg);
        if (l < LAYERS - 1) {
            // tail + fused x_next = h_new @ cf_w1[l+1]; also re-zeros agg
            node_gemm2_mfma<true><<<dim3(rowTiles, 1), 256, 0, stream>>>(
                agg,
                nwhi + (size_t)(3 + l) * 16384, nwlo + (size_t)(3 + l) * 16384, cf_b2 + (size_t)l * H,
                nwhi + (size_t)(6 + l) * 16384, nwlo + (size_t)(6 + l) * 16384, lin_b + (size_t)l * H,
                nwhi + (size_t)(l + 1) * 16384, nwlo + (size_t)(l + 1) * 16384,
                h, x, N_NODES);
        } else {
            node_gemm2_mfma<false><<<dim3(rowTiles, 1), 256, 0, stream>>>(
                agg,
                nwhi + (size_t)(3 + l) * 16384, nwlo + (size_t)(3 + l) * 16384, cf_b2 + (size_t)l * H,
                nwhi + (size_t)(6 + l) * 16384, nwlo + (size_t)(6 + l) * 16384, lin_b + (size_t)l * H,
                nullptr, nullptr,
                h, nullptr, N_NODES);
        }
    }

    hipMemsetAsync(pooled, 0, (size_t)G_GRAPHS * 5 * H * sizeof(float), stream);
    node_gemm_mfma<F_BIAS | F_POOL><<<dim3(rowTiles, 5), 256, 0, stream>>>(
        h, nwhi + (size_t)9 * 16384, nwlo + (size_t)9 * 16384, ro_b1, pooled, batch, N_NODES, 5 * H,
        nullptr, nullptr, nullptr);
    final_out<<<G_GRAPHS, 128, 0, stream>>>(pooled, ro_w2, ro_b2, ro_w3, ro_b3, out);
}